// Round 1
// baseline (297.081 us; speedup 1.0000x reference)
//
#include <hip/hip_runtime.h>

// Problem shape (fixed by setup_inputs): [B=32, C=1, H=1024, W=1024] fp32.
constexpr int B  = 32;
constexpr int HW = 1024 * 1024;

// One thread per 4 consecutive pixels. Loops over the 32 batch slices,
// accumulating per-pixel batch-sums (for the mask) and the three scalar
// reductions in registers -> single pass, each input element read once.
__global__ __launch_bounds__(256) void pra_main_kernel(
    const float* __restrict__ est,
    const float* __restrict__ gt,
    double* __restrict__ acc)  // acc[0]=diff2 acc[1]=G2 acc[2]=H2
{
    const int pix4 = blockIdx.x * blockDim.x + threadIdx.x;  // 0 .. HW/4-1
    const float4* est4 = reinterpret_cast<const float4*>(est);
    const float4* gt4  = reinterpret_cast<const float4*>(gt);

    float4 se = make_float4(0.f, 0.f, 0.f, 0.f);   // per-pixel sum est
    float4 sg = make_float4(0.f, 0.f, 0.f, 0.f);   // per-pixel sum gt
    float4 q  = make_float4(0.f, 0.f, 0.f, 0.f);   // per-pixel sum est^2
    float  d2 = 0.f;                               // sum (est-gt)^2 (4 pixels)

    #pragma unroll 4
    for (int b = 0; b < B; ++b) {
        const size_t idx = (size_t)b * (HW / 4) + pix4;
        float4 e = est4[idx];
        float4 g = gt4[idx];
        se.x += e.x; se.y += e.y; se.z += e.z; se.w += e.w;
        sg.x += g.x; sg.y += g.y; sg.z += g.z; sg.w += g.w;
        q.x  += e.x * e.x; q.y += e.y * e.y; q.z += e.z * e.z; q.w += e.w * e.w;
        float dx = e.x - g.x, dy = e.y - g.y, dz = e.z - g.z, dw = e.w - g.w;
        d2 += dx * dx + dy * dy + dz * dz + dw * dw;
    }

    float g2 = q.x + q.y + q.z + q.w;
    float h2 = (se.x > sg.x ? q.x : 0.f) + (se.y > sg.y ? q.y : 0.f) +
               (se.z > sg.z ? q.z : 0.f) + (se.w > sg.w ? q.w : 0.f);

    // Wave (64-lane) butterfly reduction.
    #pragma unroll
    for (int off = 32; off > 0; off >>= 1) {
        d2 += __shfl_down(d2, off);
        g2 += __shfl_down(g2, off);
        h2 += __shfl_down(h2, off);
    }

    __shared__ float sd[4], sG[4], sH[4];
    const int wave = threadIdx.x >> 6;
    const int lane = threadIdx.x & 63;
    if (lane == 0) { sd[wave] = d2; sG[wave] = g2; sH[wave] = h2; }
    __syncthreads();
    if (threadIdx.x == 0) {
        float D = sd[0] + sd[1] + sd[2] + sd[3];
        float G = sG[0] + sG[1] + sG[2] + sG[3];
        float H = sH[0] + sH[1] + sH[2] + sH[3];
        atomicAdd(&acc[0], (double)D);
        atomicAdd(&acc[1], (double)G);
        atomicAdd(&acc[2], (double)H);
    }
}

__global__ void pra_final_kernel(const double* __restrict__ acc,
                                 float* __restrict__ out)
{
    if (threadIdx.x == 0 && blockIdx.x == 0) {
        double d2 = acc[0], g2 = acc[1], h2 = acc[2];
        out[0] = (float)(d2 / g2 + 0.1 * (d2 / h2));
    }
}

extern "C" void kernel_launch(void* const* d_in, const int* in_sizes, int n_in,
                              void* d_out, int out_size, void* d_ws, size_t ws_size,
                              hipStream_t stream)
{
    const float* d_est = (const float*)d_in[0];
    const float* d_gt  = (const float*)d_in[1];
    float* out = (float*)d_out;
    double* acc = (double*)d_ws;

    // d_ws is poisoned to 0xAA before every launch -> zero the accumulators.
    hipMemsetAsync(acc, 0, 3 * sizeof(double), stream);

    const int threads = 256;
    const int grid = (HW / 4) / threads;  // 1024 blocks
    pra_main_kernel<<<grid, threads, 0, stream>>>(d_est, d_gt, acc);
    pra_final_kernel<<<1, 64, 0, stream>>>(acc, out);
}

// Round 2
// 287.541 us; speedup vs baseline: 1.0332x; 1.0332x over previous
//
#include <hip/hip_runtime.h>

// Problem shape (fixed by setup_inputs): [B=32, C=1, H=1024, W=1024] fp32.
constexpr int B   = 32;
constexpr int HW  = 1024 * 1024;
constexpr int NP4 = HW / 4;      // 262144 float4 pixel-groups per slice
constexpr int SPLIT = 4;         // batch-dim split within a block
constexpr int PT  = 128;         // pix4-threads per block
constexpr int TPB = SPLIT * PT;  // 512 threads
constexpr int BPT = B / SPLIT;   // 8 batch slices per thread

// Block layout: threadIdx.x = s*PT + t.  Sub-group s handles batches
// [s*BPT, (s+1)*BPT) for pixel-group pix4 = blockIdx.x*PT + t.
// Per-pixel partials (sum(e-g), sum(e^2)) are exchanged through LDS so the
// mask (sum_b e > sum_b g  <=>  sum_b (e-g) > 0) and H2 are computed without
// a second global pass. d2/G2 are pure scalars -> reduced locally by all.
__global__ __launch_bounds__(TPB) void pra_main_kernel(
    const float* __restrict__ est,
    const float* __restrict__ gt,
    double* __restrict__ acc)  // acc[0]=diff2 acc[1]=G2 acc[2]=H2
{
    const int t = threadIdx.x & (PT - 1);
    const int s = threadIdx.x / PT;
    const int pix4 = blockIdx.x * PT + t;
    const float4* est4 = reinterpret_cast<const float4*>(est);
    const float4* gt4  = reinterpret_cast<const float4*>(gt);

    float4 dse = make_float4(0.f, 0.f, 0.f, 0.f);  // sum (e - g) per pixel
    float4 q   = make_float4(0.f, 0.f, 0.f, 0.f);  // sum e^2 per pixel
    float  d2  = 0.f;                              // sum (e-g)^2

    const int b0 = s * BPT;
    #pragma unroll
    for (int half = 0; half < BPT / 4; ++half) {
        // Batch 4 iterations of loads -> 8 float4 loads in flight per wave.
        float4 e[4], g[4];
        #pragma unroll
        for (int j = 0; j < 4; ++j) {
            const size_t idx = (size_t)(b0 + half * 4 + j) * NP4 + pix4;
            e[j] = est4[idx];
            g[j] = gt4[idx];
        }
        #pragma unroll
        for (int j = 0; j < 4; ++j) {
            float dx = e[j].x - g[j].x, dy = e[j].y - g[j].y;
            float dz = e[j].z - g[j].z, dw = e[j].w - g[j].w;
            dse.x += dx; dse.y += dy; dse.z += dz; dse.w += dw;
            q.x += e[j].x * e[j].x; q.y += e[j].y * e[j].y;
            q.z += e[j].z * e[j].z; q.w += e[j].w * e[j].w;
            d2 += dx * dx + dy * dy + dz * dz + dw * dw;
        }
    }

    // Exchange per-pixel partials: sub-groups 1..3 publish, sub-group 0 combines.
    __shared__ float4 Ldse[SPLIT - 1][PT];
    __shared__ float4 Lq[SPLIT - 1][PT];
    if (s > 0) { Ldse[s - 1][t] = dse; Lq[s - 1][t] = q; }
    __syncthreads();

    float g2 = q.x + q.y + q.z + q.w;
    float h2 = 0.f;
    if (s == 0) {
        float4 dt = dse, qt = q;
        #pragma unroll
        for (int k = 0; k < SPLIT - 1; ++k) {
            float4 a = Ldse[k][t], b4 = Lq[k][t];
            dt.x += a.x; dt.y += a.y; dt.z += a.z; dt.w += a.w;
            qt.x += b4.x; qt.y += b4.y; qt.z += b4.z; qt.w += b4.w;
        }
        h2 = (dt.x > 0.f ? qt.x : 0.f) + (dt.y > 0.f ? qt.y : 0.f) +
             (dt.z > 0.f ? qt.z : 0.f) + (dt.w > 0.f ? qt.w : 0.f);
    }

    // Block reduction: wave butterfly then cross-wave via LDS.
    #pragma unroll
    for (int off = 32; off > 0; off >>= 1) {
        d2 += __shfl_down(d2, off);
        g2 += __shfl_down(g2, off);
        h2 += __shfl_down(h2, off);
    }
    __shared__ float rd[TPB / 64], rg[TPB / 64], rh[TPB / 64];
    const int wave = threadIdx.x >> 6;
    const int lane = threadIdx.x & 63;
    if (lane == 0) { rd[wave] = d2; rg[wave] = g2; rh[wave] = h2; }
    __syncthreads();
    if (threadIdx.x == 0) {
        float D = 0.f, G = 0.f, H = 0.f;
        #pragma unroll
        for (int k = 0; k < TPB / 64; ++k) { D += rd[k]; G += rg[k]; H += rh[k]; }
        atomicAdd(&acc[0], (double)D);
        atomicAdd(&acc[1], (double)G);
        atomicAdd(&acc[2], (double)H);
    }
}

__global__ void pra_final_kernel(const double* __restrict__ acc,
                                 float* __restrict__ out)
{
    if (threadIdx.x == 0 && blockIdx.x == 0) {
        double d2 = acc[0], g2 = acc[1], h2 = acc[2];
        out[0] = (float)(d2 / g2 + 0.1 * (d2 / h2));
    }
}

extern "C" void kernel_launch(void* const* d_in, const int* in_sizes, int n_in,
                              void* d_out, int out_size, void* d_ws, size_t ws_size,
                              hipStream_t stream)
{
    const float* d_est = (const float*)d_in[0];
    const float* d_gt  = (const float*)d_in[1];
    float* out = (float*)d_out;
    double* acc = (double*)d_ws;

    // d_ws is poisoned to 0xAA before every launch -> zero the accumulators.
    hipMemsetAsync(acc, 0, 3 * sizeof(double), stream);

    const int grid = NP4 / PT;  // 2048 blocks
    pra_main_kernel<<<grid, TPB, 0, stream>>>(d_est, d_gt, acc);
    pra_final_kernel<<<1, 64, 0, stream>>>(acc, out);
}

// Round 4
// 272.468 us; speedup vs baseline: 1.0903x; 1.0553x over previous
//
#include <hip/hip_runtime.h>

// Problem shape (fixed by setup_inputs): [B=32, C=1, H=1024, W=1024] fp32.
constexpr int B   = 32;
constexpr int HW  = 1024 * 1024;
constexpr int NP4 = HW / 4;   // float4 pixel-groups per slice

// Native clang vector type — __builtin_nontemporal_load requires a real
// vector type, not HIP's float4 struct.
typedef float floatx4 __attribute__((ext_vector_type(4)));

__device__ __forceinline__ floatx4 nt_load(const floatx4* p) {
    return __builtin_nontemporal_load(p);
}

// One thread per 4 consecutive pixels; in-register loop over the 32 batch
// slices with explicit depth-2 prefetch (loads for b+2 issued while
// computing on b) so each wave keeps ~4 KB of loads in flight continuously
// instead of draining vmcnt(0) every iteration.
__global__ __launch_bounds__(256) void pra_main_kernel(
    const float* __restrict__ est,
    const float* __restrict__ gt,
    double* __restrict__ acc)  // acc[0]=diff2 acc[1]=G2 acc[2]=H2
{
    const int pix4 = blockIdx.x * blockDim.x + threadIdx.x;  // 0 .. NP4-1
    const floatx4* e_ptr = reinterpret_cast<const floatx4*>(est) + pix4;
    const floatx4* g_ptr = reinterpret_cast<const floatx4*>(gt) + pix4;

    floatx4 dse = {0.f, 0.f, 0.f, 0.f};  // sum (e-g) per pixel
    floatx4 q   = {0.f, 0.f, 0.f, 0.f};  // sum e^2 per pixel
    float   d2  = 0.f;                   // sum (e-g)^2

    // Prefetch pipeline, depth 2.
    floatx4 e0 = nt_load(e_ptr);        floatx4 g0 = nt_load(g_ptr);
    floatx4 e1 = nt_load(e_ptr + NP4);  floatx4 g1 = nt_load(g_ptr + NP4);

    #pragma unroll
    for (int b = 0; b < B; ++b) {
        floatx4 e = e0, g = g0;
        e0 = e1; g0 = g1;
        if (b + 2 < B) {
            e1 = nt_load(e_ptr + (size_t)(b + 2) * NP4);
            g1 = nt_load(g_ptr + (size_t)(b + 2) * NP4);
        }
        floatx4 d = e - g;
        dse += d;
        q   += e * e;
        floatx4 dd = d * d;
        d2 += dd.x + dd.y + dd.z + dd.w;
    }

    // mask: sum_b e > sum_b g  <=>  sum_b (e-g) > 0
    float g2 = q.x + q.y + q.z + q.w;
    float h2 = (dse.x > 0.f ? q.x : 0.f) + (dse.y > 0.f ? q.y : 0.f) +
               (dse.z > 0.f ? q.z : 0.f) + (dse.w > 0.f ? q.w : 0.f);

    // Wave (64-lane) butterfly reduction.
    #pragma unroll
    for (int off = 32; off > 0; off >>= 1) {
        d2 += __shfl_down(d2, off);
        g2 += __shfl_down(g2, off);
        h2 += __shfl_down(h2, off);
    }

    __shared__ float sd[4], sG[4], sH[4];
    const int wave = threadIdx.x >> 6;
    const int lane = threadIdx.x & 63;
    if (lane == 0) { sd[wave] = d2; sG[wave] = g2; sH[wave] = h2; }
    __syncthreads();
    if (threadIdx.x == 0) {
        float D = sd[0] + sd[1] + sd[2] + sd[3];
        float G = sG[0] + sG[1] + sG[2] + sG[3];
        float H = sH[0] + sH[1] + sH[2] + sH[3];
        atomicAdd(&acc[0], (double)D);
        atomicAdd(&acc[1], (double)G);
        atomicAdd(&acc[2], (double)H);
    }
}

__global__ void pra_final_kernel(const double* __restrict__ acc,
                                 float* __restrict__ out)
{
    if (threadIdx.x == 0 && blockIdx.x == 0) {
        double d2 = acc[0], g2 = acc[1], h2 = acc[2];
        out[0] = (float)(d2 / g2 + 0.1 * (d2 / h2));
    }
}

extern "C" void kernel_launch(void* const* d_in, const int* in_sizes, int n_in,
                              void* d_out, int out_size, void* d_ws, size_t ws_size,
                              hipStream_t stream)
{
    const float* d_est = (const float*)d_in[0];
    const float* d_gt  = (const float*)d_in[1];
    float* out = (float*)d_out;
    double* acc = (double*)d_ws;

    // d_ws is poisoned to 0xAA before every launch -> zero the accumulators.
    (void)hipMemsetAsync(acc, 0, 3 * sizeof(double), stream);

    const int threads = 256;
    const int grid = NP4 / threads;  // 1024 blocks
    pra_main_kernel<<<grid, threads, 0, stream>>>(d_est, d_gt, acc);
    pra_final_kernel<<<1, 64, 0, stream>>>(acc, out);
}

// Round 5
// 271.098 us; speedup vs baseline: 1.0958x; 1.0051x over previous
//
#include <hip/hip_runtime.h>

// Problem shape (fixed by setup_inputs): [B=32, C=1, H=1024, W=1024] fp32.
constexpr int B   = 32;
constexpr int HW  = 1024 * 1024;
constexpr int NP4 = HW / 4;   // float4 pixel-groups per slice
constexpr int DEPTH = 4;      // prefetch pipeline depth (batch slices ahead)

// Native clang vector type — __builtin_nontemporal_load requires a real
// vector type, not HIP's float4 struct.
typedef float floatx4 __attribute__((ext_vector_type(4)));

__device__ __forceinline__ floatx4 nt_load(const floatx4* p) {
    return __builtin_nontemporal_load(p);
}

// One thread per 4 consecutive pixels; in-register loop over the 32 batch
// slices with explicit depth-4 prefetch: loads for slice b+4 are issued
// while computing on slice b, keeping 8 dwordx4 loads (8 KB/wave)
// continuously in flight. 16 waves/CU -> ~128 KB in flight per CU.
__global__ __launch_bounds__(256) void pra_main_kernel(
    const float* __restrict__ est,
    const float* __restrict__ gt,
    double* __restrict__ acc)  // acc[0]=diff2 acc[1]=G2 acc[2]=H2
{
    const int pix4 = blockIdx.x * blockDim.x + threadIdx.x;  // 0 .. NP4-1
    const floatx4* e_ptr = reinterpret_cast<const floatx4*>(est) + pix4;
    const floatx4* g_ptr = reinterpret_cast<const floatx4*>(gt) + pix4;

    floatx4 dse = {0.f, 0.f, 0.f, 0.f};  // sum (e-g) per pixel
    floatx4 q   = {0.f, 0.f, 0.f, 0.f};  // sum e^2 per pixel
    float   d2  = 0.f;                   // sum (e-g)^2

    floatx4 eb[DEPTH], gb[DEPTH];
    #pragma unroll
    for (int j = 0; j < DEPTH; ++j) {
        eb[j] = nt_load(e_ptr + (size_t)j * NP4);
        gb[j] = nt_load(g_ptr + (size_t)j * NP4);
    }

    #pragma unroll
    for (int b = 0; b < B; ++b) {
        const int slot = b % DEPTH;
        floatx4 e = eb[slot], g = gb[slot];
        if (b + DEPTH < B) {
            eb[slot] = nt_load(e_ptr + (size_t)(b + DEPTH) * NP4);
            gb[slot] = nt_load(g_ptr + (size_t)(b + DEPTH) * NP4);
        }
        floatx4 d = e - g;
        dse += d;
        q   += e * e;
        floatx4 dd = d * d;
        d2 += dd.x + dd.y + dd.z + dd.w;
    }

    // mask: sum_b e > sum_b g  <=>  sum_b (e-g) > 0
    float g2 = q.x + q.y + q.z + q.w;
    float h2 = (dse.x > 0.f ? q.x : 0.f) + (dse.y > 0.f ? q.y : 0.f) +
               (dse.z > 0.f ? q.z : 0.f) + (dse.w > 0.f ? q.w : 0.f);

    // Wave (64-lane) butterfly reduction.
    #pragma unroll
    for (int off = 32; off > 0; off >>= 1) {
        d2 += __shfl_down(d2, off);
        g2 += __shfl_down(g2, off);
        h2 += __shfl_down(h2, off);
    }

    __shared__ float sd[4], sG[4], sH[4];
    const int wave = threadIdx.x >> 6;
    const int lane = threadIdx.x & 63;
    if (lane == 0) { sd[wave] = d2; sG[wave] = g2; sH[wave] = h2; }
    __syncthreads();
    if (threadIdx.x == 0) {
        float D = sd[0] + sd[1] + sd[2] + sd[3];
        float G = sG[0] + sG[1] + sG[2] + sG[3];
        float H = sH[0] + sH[1] + sH[2] + sH[3];
        atomicAdd(&acc[0], (double)D);
        atomicAdd(&acc[1], (double)G);
        atomicAdd(&acc[2], (double)H);
    }
}

__global__ void pra_final_kernel(const double* __restrict__ acc,
                                 float* __restrict__ out)
{
    if (threadIdx.x == 0 && blockIdx.x == 0) {
        double d2 = acc[0], g2 = acc[1], h2 = acc[2];
        out[0] = (float)(d2 / g2 + 0.1 * (d2 / h2));
    }
}

extern "C" void kernel_launch(void* const* d_in, const int* in_sizes, int n_in,
                              void* d_out, int out_size, void* d_ws, size_t ws_size,
                              hipStream_t stream)
{
    const float* d_est = (const float*)d_in[0];
    const float* d_gt  = (const float*)d_in[1];
    float* out = (float*)d_out;
    double* acc = (double*)d_ws;

    // d_ws is poisoned to 0xAA before every launch -> zero the accumulators.
    (void)hipMemsetAsync(acc, 0, 3 * sizeof(double), stream);

    const int threads = 256;
    const int grid = NP4 / threads;  // 1024 blocks
    pra_main_kernel<<<grid, threads, 0, stream>>>(d_est, d_gt, acc);
    pra_final_kernel<<<1, 64, 0, stream>>>(acc, out);
}